// Round 21
// baseline (601.349 us; speedup 1.0000x reference)
//
#include <hip/hip_runtime.h>
#include <hip/hip_bf16.h>

#define NB 2048
#define NF 6144
#define ND 768
#define BM 256
#define BN 192
#define BK 64
#define SPLITK 2
#define KCH (NF / SPLITK)  // 3072 per block
#define NTIL (KCH / BK)    // 48 K-tiles per block

// LDS: A 256 rows x 128 B = 32 KB; B 192 rows x 128 B = 24 KB; dbuf = 112 KB
#define ABYTES (BM * 128)
#define BBYTES (BN * 128)
#define BUFBYTES (ABYTES + BBYTES)

typedef __attribute__((ext_vector_type(8))) __bf16 bf16x8;
typedef __attribute__((ext_vector_type(4))) float f32x4;

// Proven layout (0 conflicts across rounds 2-20): 128B rows of 64 bf16,
// 16B-slot 3-bit swizzle slot = (k>>3) ^ (row&7) ^ ((row>>2)&7)
__device__ __forceinline__ char* lds_addr(char* base, int row, int k) {
  const int blk = ((k >> 3) ^ (row & 7) ^ ((row >> 2) & 7)) & 7;
  return base + row * 128 + (blk << 4) + ((k & 7) << 1);
}

#define SBAR0() __builtin_amdgcn_sched_barrier(0)
#define LGKM(N)                                              \
  do {                                                       \
    asm volatile("s_waitcnt lgkmcnt(" #N ")" ::: "memory");  \
    SBAR0();                                                 \
  } while (0)

// out[b,d] = sum_l bias[l,d]  (clears 0xAA poison deterministically)
__global__ __launch_bounds__(256) void bias_init_kernel(
    const float* __restrict__ bias, const int* __restrict__ lidx,
    float* __restrict__ out) {
  int n = lidx[0] + 1;
  int i = blockIdx.x * 256 + threadIdx.x;
  if (i >= NB * ND) return;
  int d = i % ND;
  float s = 0.f;
  for (int l = 0; l < n; ++l) s += bias[l * ND + d];
  out[i] = s;
}

// R8 structure (best total 468.6-479 us, reproduced 4x) + R13's fragment
// software-pipeline grafted onto the fused path: bF pair p+1 stays in
// flight (counted lgkmcnt(4)) under MFMA cluster p, removing 2 of 3 full
// LDS drains per tile. Register check: R8 = 128 VGPR + 96 acc = 224; the
// two extra bF sets add 16 -> ~240 <= 256 at 2 waves/SIMD; unlike
// R15/R17/R19 no staging register lives across a barrier.
__global__ __launch_bounds__(512, 2) void gemm_kernel(
    const float* __restrict__ acts, const float* __restrict__ W,
    const int* __restrict__ lidx, float* __restrict__ out, int nwg) {
  extern __shared__ char cbuf[];  // 2 * BUFBYTES

  const int chunk = nwg >> 3;  // 96
  const int swz = (blockIdx.x & 7) * chunk + (blockIdx.x >> 3);
  const int by = swz & 3;  // id = by + 4*(m + 8*(ks + 2*l))
  int rem = swz >> 2;
  const int m = rem & 7; rem >>= 3;
  const int ks = rem & 1; rem >>= 1;
  const int l = rem;
  if (l > lidx[0]) return;  // uniform exit before any barrier

  const int brow = m * BM;
  const int ncol = by * BN;
  const int k0 = ks * KCH;

  const int tid = threadIdx.x;
  const int lane = tid & 63;
  const int wid = tid >> 6;          // 8 waves: 4m x 2n
  const int wrow = (wid >> 1) * 64;  // 0,64,128,192
  const int wcol = (wid & 1) * 96;   // 0,96

  f32x4 acc[4][6];
#pragma unroll
  for (int i = 0; i < 4; ++i)
#pragma unroll
    for (int j = 0; j < 6; ++j) acc[i][j] = (f32x4){0.f, 0.f, 0.f, 0.f};

  // A staging: thread -> (row = tid>>3 (+64 per pass p<4), 8 consecutive k)
  const int s_arow = tid >> 3;
  const int s_ak = (tid & 7) * 8;
  // B staging: threads 0..383: (4 consecutive d, 8 consecutive k)
  const bool bstage = tid < 384;
  const int s_bd = (tid % 48) * 4;
  const int s_bk = (tid / 48) * 8;

  const float* Aptr =
      acts + (size_t)l * NB * NF + (size_t)(brow + s_arow) * NF + k0 + s_ak;
  const float* Bptr =
      W + (size_t)l * NF * ND + (size_t)(k0 + s_bk) * ND + (ncol + s_bd);

  float4 av[4][2];  // A: 4 row-passes x 8 k (32 VGPR)
  float4 bv[8];     // B: 8 k-rows x 4 d   (32 VGPR, waves 0-5)

  auto LOADS = [&](int kb) {
#pragma unroll
    for (int p = 0; p < 4; ++p) {
      av[p][0] = *(const float4*)(Aptr + (size_t)(64 * p) * NF + kb);
      av[p][1] = *(const float4*)(Aptr + (size_t)(64 * p) * NF + kb + 4);
    }
    if (bstage) {
#pragma unroll
      for (int j = 0; j < 8; ++j)
        bv[j] = *(const float4*)(Bptr + (size_t)(kb + j) * ND);
    }
  };

  auto STORE = [&](char* cA_, char* cB_) {
#pragma unroll
    for (int p = 0; p < 4; ++p) {
      bf16x8 h;
      h[0] = (__bf16)av[p][0].x; h[1] = (__bf16)av[p][0].y;
      h[2] = (__bf16)av[p][0].z; h[3] = (__bf16)av[p][0].w;
      h[4] = (__bf16)av[p][1].x; h[5] = (__bf16)av[p][1].y;
      h[6] = (__bf16)av[p][1].z; h[7] = (__bf16)av[p][1].w;
      *(bf16x8*)lds_addr(cA_, s_arow + 64 * p, s_ak) = h;
    }
    if (bstage) {
#pragma unroll
      for (int dd = 0; dd < 4; ++dd) {
        bf16x8 h;
#pragma unroll
        for (int j = 0; j < 8; ++j) h[j] = (__bf16)bv[j][dd];
        *(bf16x8*)lds_addr(cB_, s_bd + dd, s_bk) = h;
      }
    }
  };

// Read one bF pair P (4 x ds_read_b128) into named regs (literal P).
#define BF_READ(dst, P)                                                   \
  _Pragma("unroll") for (int ni = 0; ni < 2; ++ni)                        \
    _Pragma("unroll") for (int s = 0; s < 2; ++s)                         \
      dst[ni][s] = *(const bf16x8*)lds_addr(                              \
          rB, wcol + (2 * (P) + ni) * 16 + (lane & 15),                   \
          s * 32 + (lane >> 4) * 8);

#define MFMA16(bf, P)                                                     \
  __builtin_amdgcn_s_setprio(1);                                          \
  _Pragma("unroll") for (int s = 0; s < 2; ++s)                           \
    _Pragma("unroll") for (int mi = 0; mi < 4; ++mi)                      \
      _Pragma("unroll") for (int ni = 0; ni < 2; ++ni)                    \
        acc[mi][2 * (P) + ni] = __builtin_amdgcn_mfma_f32_16x16x32_bf16(  \
            aF[mi][s], bf[ni][s], acc[mi][2 * (P) + ni], 0, 0, 0);        \
  __builtin_amdgcn_s_setprio(0);                                          \
  SBAR0();

  // ---- prologue: tile 0 staged into buf0 (self-waiting, once) ----
  LOADS(0);
  STORE(cbuf, cbuf + ABYTES);

  for (int t = 0; t < NTIL; ++t) {
    const int cur = t & 1;
    char* rA = cbuf + (size_t)cur * BUFBYTES;
    char* rB = rA + ABYTES;
    char* wA = cbuf + (size_t)(cur ^ 1) * BUFBYTES;
    char* wB = wA + ABYTES;

    // tile boundary: writes visible + reads done (lgkm drain); vmcnt NOT
    // drained -> next tile's global loads stay in flight across the barrier.
    LGKM(0);
    __builtin_amdgcn_s_barrier();
    SBAR0();

    if (t + 1 < NTIL) LOADS((t + 1) * BK);  // consumed after 3 MFMA phases
    SBAR0();

    // ---- fragment pipeline (R13-validated): aF + bFa + bFb issued;
    //      counted lgkmcnt(4) leaves the NEXT pair in flight under MFMA ----
    bf16x8 aF[4][2];
#pragma unroll
    for (int mi = 0; mi < 4; ++mi)
#pragma unroll
      for (int s = 0; s < 2; ++s)
        aF[mi][s] = *(const bf16x8*)lds_addr(
            rA, wrow + mi * 16 + (lane & 15), s * 32 + (lane >> 4) * 8);
    bf16x8 bFa[2][2], bFb[2][2], bFc[2][2];
    BF_READ(bFa, 0)
    BF_READ(bFb, 1)
    SBAR0();
    LGKM(4);        // aF + bFa landed (DS ops complete in order); bFb flying
    MFMA16(bFa, 0)

    BF_READ(bFc, 2) // in flight under cluster 1
    SBAR0();
    LGKM(4);        // bFb landed
    MFMA16(bFb, 1)

    LGKM(0);        // bFc landed
    MFMA16(bFc, 2)

    // cvt+write next tile (reg-dep vmcnt wait; loads are ~3 phases old)
    if (t + 1 < NTIL) STORE(wA, wB);
  }

#undef BF_READ
#undef MFMA16

  // ---- epilogue: atomic accumulate (24 blocks collide: 12L x 2K) ----
  // C/D layout (m89-verified): col = lane&15, row = (lane>>4)*4 + j
  const int orow = brow + wrow + ((lane >> 4) << 2);
  const int ocol = ncol + wcol + (lane & 15);
#pragma unroll
  for (int mi = 0; mi < 4; ++mi)
#pragma unroll
    for (int ni = 0; ni < 6; ++ni)
#pragma unroll
      for (int j = 0; j < 4; ++j)
        atomicAdd(out + (size_t)(orow + mi * 16 + j) * ND + (ocol + ni * 16),
                  acc[mi][ni][j]);
}

extern "C" void kernel_launch(void* const* d_in, const int* in_sizes, int n_in,
                              void* d_out, int out_size, void* d_ws, size_t ws_size,
                              hipStream_t stream) {
  const float* acts = (const float*)d_in[0];
  const float* W    = (const float*)d_in[1];
  const float* bias = (const float*)d_in[2];
  const int*   lidx = (const int*)d_in[3];
  float* out = (float*)d_out;

  const int L = in_sizes[0] / (NB * NF);               // 12
  const int nwg = (ND / BN) * (NB / BM) * SPLITK * L;  // 768 = 3 x 256 CUs

  hipFuncSetAttribute((const void*)gemm_kernel,
                      hipFuncAttributeMaxDynamicSharedMemorySize, 2 * BUFBYTES);

  bias_init_kernel<<<dim3((NB * ND + 255) / 256), 256, 0, stream>>>(bias, lidx, out);
  gemm_kernel<<<dim3(nwg), 512, 2 * BUFBYTES, stream>>>(acts, W, lidx, out, nwg);
}

// Round 22
// 477.413 us; speedup vs baseline: 1.2596x; 1.2596x over previous
//
#include <hip/hip_runtime.h>
#include <hip/hip_bf16.h>

#define NB 2048
#define NF 6144
#define ND 768
#define BM 256
#define BN 192
#define BK 64
#define SPLITK 2
#define KCH (NF / SPLITK)  // 3072 per block
#define NTIL (KCH / BK)    // 48 K-tiles per block

// LDS: A 256 rows x 128 B = 32 KB; B 192 rows x 128 B = 24 KB; dbuf = 112 KB
#define ABYTES (BM * 128)
#define BBYTES (BN * 128)
#define BUFBYTES (ABYTES + BBYTES)

typedef __attribute__((ext_vector_type(8))) __bf16 bf16x8;
typedef __attribute__((ext_vector_type(4))) float f32x4;

// Proven layout (0 conflicts across rounds 2-20): 128B rows of 64 bf16,
// 16B-slot 3-bit swizzle slot = (k>>3) ^ (row&7) ^ ((row>>2)&7)
__device__ __forceinline__ char* lds_addr(char* base, int row, int k) {
  const int blk = ((k >> 3) ^ (row & 7) ^ ((row >> 2) & 7)) & 7;
  return base + row * 128 + (blk << 4) + ((k & 7) << 1);
}

#define SBAR0() __builtin_amdgcn_sched_barrier(0)
#define LGKM0()                                            \
  do {                                                     \
    asm volatile("s_waitcnt lgkmcnt(0)" ::: "memory");     \
    SBAR0();                                               \
  } while (0)

// out[b,d] = sum_l bias[l,d]  (clears 0xAA poison deterministically)
__global__ __launch_bounds__(256) void bias_init_kernel(
    const float* __restrict__ bias, const int* __restrict__ lidx,
    float* __restrict__ out) {
  int n = lidx[0] + 1;
  int i = blockIdx.x * 256 + threadIdx.x;
  if (i >= NB * ND) return;
  int d = i % ND;
  float s = 0.f;
  for (int l = 0; l < n; ++l) s += bias[l * ND + d];
  out[i] = s;
}

// FINAL kernel = R8 structure (best measured total: 468.6-479 us, reproduced
// four times: rounds 8, 16, 18, 20). 256x192 tile, 8 waves (4m x 2n), BK=64,
// split-K x2, LDS double-buffer, ONE lgkm-only barrier per K-tile (global
// loads stay in flight across it), by-fastest XCD decode (FETCH 1.27GB ->
// 405MB), 3 setprio-wrapped MFMA phases per tile.
//
// Design-space map, rounds 9-21 (11 consecutive alternatives measured WORSE):
//  - ANY added register pressure spills: deeper reg pipelines (R3/R15),
//    wave specialization (R17), 12-wave rebalance (R19), even +16 regs of
//    fragment pipelining (R21: WRITE 147->172MB, 601us). The allocator
//    holds this kernel at the 128-VGPR class; R8 is the maximal schedule
//    that fits (single staging set, consumed within the tile body).
//  - extra per-phase barriers cost more than they overlap at 8 lockstep
//    waves (R9, R12); wave-schedule stagger duplicates live ranges (R11)
//  - prepass conversions (A or W^T) pay more HBM tax than they save in-loop
//    (R10: 637, R13: 543, R14: 498 vs this 469)
//  - sub-128B-row LDS write patterns reintroduce bank conflicts (R5, R12,
//    R19); only this 128B-row 3-bit-XOR layout measured 0 conflicts
//  - counted lgkmcnt fragment pipelining miscounts against the fused STORE's
//    ds_writes sharing the lgkm queue (R21: MfmaUtil 18->14.7)
__global__ __launch_bounds__(512, 2) void gemm_kernel(
    const float* __restrict__ acts, const float* __restrict__ W,
    const int* __restrict__ lidx, float* __restrict__ out, int nwg) {
  extern __shared__ char cbuf[];  // 2 * BUFBYTES

  const int chunk = nwg >> 3;  // 96
  const int swz = (blockIdx.x & 7) * chunk + (blockIdx.x >> 3);
  const int by = swz & 3;  // id = by + 4*(m + 8*(ks + 2*l))
  int rem = swz >> 2;
  const int m = rem & 7; rem >>= 3;
  const int ks = rem & 1; rem >>= 1;
  const int l = rem;
  if (l > lidx[0]) return;  // uniform exit before any barrier

  const int brow = m * BM;
  const int ncol = by * BN;
  const int k0 = ks * KCH;

  const int tid = threadIdx.x;
  const int lane = tid & 63;
  const int wid = tid >> 6;          // 8 waves: 4m x 2n
  const int wrow = (wid >> 1) * 64;  // 0,64,128,192
  const int wcol = (wid & 1) * 96;   // 0,96

  f32x4 acc[4][6];
#pragma unroll
  for (int i = 0; i < 4; ++i)
#pragma unroll
    for (int j = 0; j < 6; ++j) acc[i][j] = (f32x4){0.f, 0.f, 0.f, 0.f};

  // A staging: thread -> (row = tid>>3 (+64 per pass p<4), 8 consecutive k)
  const int s_arow = tid >> 3;
  const int s_ak = (tid & 7) * 8;
  // B staging: threads 0..383: (4 consecutive d, 8 consecutive k)
  const bool bstage = tid < 384;
  const int s_bd = (tid % 48) * 4;
  const int s_bk = (tid / 48) * 8;

  const float* Aptr =
      acts + (size_t)l * NB * NF + (size_t)(brow + s_arow) * NF + k0 + s_ak;
  const float* Bptr =
      W + (size_t)l * NF * ND + (size_t)(k0 + s_bk) * ND + (ncol + s_bd);

  float4 av[4][2];  // A: 4 row-passes x 8 k (32 VGPR)
  float4 bv[8];     // B: 8 k-rows x 4 d   (32 VGPR, waves 0-5)

  auto LOADS = [&](int kb) {
#pragma unroll
    for (int p = 0; p < 4; ++p) {
      av[p][0] = *(const float4*)(Aptr + (size_t)(64 * p) * NF + kb);
      av[p][1] = *(const float4*)(Aptr + (size_t)(64 * p) * NF + kb + 4);
    }
    if (bstage) {
#pragma unroll
      for (int j = 0; j < 8; ++j)
        bv[j] = *(const float4*)(Bptr + (size_t)(kb + j) * ND);
    }
  };

  auto STORE = [&](char* cA_, char* cB_) {
#pragma unroll
    for (int p = 0; p < 4; ++p) {
      bf16x8 h;
      h[0] = (__bf16)av[p][0].x; h[1] = (__bf16)av[p][0].y;
      h[2] = (__bf16)av[p][0].z; h[3] = (__bf16)av[p][0].w;
      h[4] = (__bf16)av[p][1].x; h[5] = (__bf16)av[p][1].y;
      h[6] = (__bf16)av[p][1].z; h[7] = (__bf16)av[p][1].w;
      *(bf16x8*)lds_addr(cA_, s_arow + 64 * p, s_ak) = h;
    }
    if (bstage) {
#pragma unroll
      for (int dd = 0; dd < 4; ++dd) {
        bf16x8 h;
#pragma unroll
        for (int j = 0; j < 8; ++j) h[j] = (__bf16)bv[j][dd];
        *(bf16x8*)lds_addr(cB_, s_bd + dd, s_bk) = h;
      }
    }
  };

  // ---- prologue: tile 0 staged into buf0 (self-waiting, once) ----
  LOADS(0);
  STORE(cbuf, cbuf + ABYTES);

  for (int t = 0; t < NTIL; ++t) {
    const int cur = t & 1;
    char* rA = cbuf + (size_t)cur * BUFBYTES;
    char* rB = rA + ABYTES;
    char* wA = cbuf + (size_t)(cur ^ 1) * BUFBYTES;
    char* wB = wA + ABYTES;

    // tile boundary: writes visible + reads done (lgkm drain); vmcnt NOT
    // drained -> next tile's global loads stay in flight across the barrier.
    LGKM0();
    __builtin_amdgcn_s_barrier();
    SBAR0();

    if (t + 1 < NTIL) LOADS((t + 1) * BK);  // consumed after 3 MFMA phases
    SBAR0();

    // A fragments for all 3 phases (read once, 32 VGPR)
    bf16x8 aF[4][2];
#pragma unroll
    for (int mi = 0; mi < 4; ++mi)
#pragma unroll
      for (int s = 0; s < 2; ++s)
        aF[mi][s] = *(const bf16x8*)lds_addr(
            rA, wrow + mi * 16 + (lane & 15), s * 32 + (lane >> 4) * 8);

    // 3 phases: each reads one B n-pair, then a 16-MFMA cluster
#pragma unroll
    for (int p = 0; p < 3; ++p) {
      bf16x8 bF[2][2];
#pragma unroll
      for (int ni = 0; ni < 2; ++ni)
#pragma unroll
        for (int s = 0; s < 2; ++s)
          bF[ni][s] = *(const bf16x8*)lds_addr(
              rB, wcol + (2 * p + ni) * 16 + (lane & 15),
              s * 32 + (lane >> 4) * 8);
      LGKM0();
      __builtin_amdgcn_s_setprio(1);
#pragma unroll
      for (int s = 0; s < 2; ++s)
#pragma unroll
        for (int mi = 0; mi < 4; ++mi)
#pragma unroll
          for (int ni = 0; ni < 2; ++ni)
            acc[mi][2 * p + ni] = __builtin_amdgcn_mfma_f32_16x16x32_bf16(
                aF[mi][s], bF[ni][s], acc[mi][2 * p + ni], 0, 0, 0);
      __builtin_amdgcn_s_setprio(0);
      SBAR0();
    }

    // cvt+write next tile (reg-dep vmcnt wait; loads are ~3 phases old)
    if (t + 1 < NTIL) STORE(wA, wB);
  }

  // ---- epilogue: atomic accumulate (24 blocks collide: 12L x 2K) ----
  // C/D layout (m89-verified): col = lane&15, row = (lane>>4)*4 + j
  const int orow = brow + wrow + ((lane >> 4) << 2);
  const int ocol = ncol + wcol + (lane & 15);
#pragma unroll
  for (int mi = 0; mi < 4; ++mi)
#pragma unroll
    for (int ni = 0; ni < 6; ++ni)
#pragma unroll
      for (int j = 0; j < 4; ++j)
        atomicAdd(out + (size_t)(orow + mi * 16 + j) * ND + (ocol + ni * 16),
                  acc[mi][ni][j]);
}

extern "C" void kernel_launch(void* const* d_in, const int* in_sizes, int n_in,
                              void* d_out, int out_size, void* d_ws, size_t ws_size,
                              hipStream_t stream) {
  const float* acts = (const float*)d_in[0];
  const float* W    = (const float*)d_in[1];
  const float* bias = (const float*)d_in[2];
  const int*   lidx = (const int*)d_in[3];
  float* out = (float*)d_out;

  const int L = in_sizes[0] / (NB * NF);               // 12
  const int nwg = (ND / BN) * (NB / BM) * SPLITK * L;  // 768 = 3 x 256 CUs

  hipFuncSetAttribute((const void*)gemm_kernel,
                      hipFuncAttributeMaxDynamicSharedMemorySize, 2 * BUFBYTES);

  bias_init_kernel<<<dim3((NB * ND + 255) / 256), 256, 0, stream>>>(bias, lidx, out);
  gemm_kernel<<<dim3(nwg), 512, 2 * BUFBYTES, stream>>>(acts, W, lidx, out, nwg);
}